// Round 6
// baseline (869.373 us; speedup 1.0000x reference)
//
#include <hip/hip_runtime.h>

typedef short bf16x8 __attribute__((ext_vector_type(8)));
typedef float f32x4 __attribute__((ext_vector_type(4)));
typedef unsigned short us4 __attribute__((ext_vector_type(4)));

#define B_ 16
#define S_ 2048
#define F_ 512
#define U_ 512
#define NROWS (B_ * S_)          // 32768

#define MFMA(a, b, c) __builtin_amdgcn_mfma_f32_16x16x32_bf16((a), (b), (c), 0, 0, 0)

__device__ __forceinline__ unsigned short f2b(float f) {
    unsigned u = __builtin_bit_cast(unsigned, f);
    return (unsigned short)((u + 0x7FFFu + ((u >> 16) & 1u)) >> 16);
}

// ---------------------------------------------------------------------------
// x fp32 -> bf16 row-major [32768][512]
// ---------------------------------------------------------------------------
__global__ __launch_bounds__(256) void conv_x(const float* __restrict__ x,
                                              unsigned short* __restrict__ xb)
{
    const size_t n8 = (size_t)NROWS * F_ / 8;
    const size_t stride = (size_t)gridDim.x * 256;
    for (size_t i = (size_t)blockIdx.x * 256 + threadIdx.x; i < n8; i += stride) {
        const float4 a = ((const float4*)x)[i * 2];
        const float4 b = ((const float4*)x)[i * 2 + 1];
        us4 lo, hi;
        lo.x = f2b(a.x); lo.y = f2b(a.y); lo.z = f2b(a.z); lo.w = f2b(a.w);
        hi.x = f2b(b.x); hi.y = f2b(b.y); hi.z = f2b(b.z); hi.w = f2b(b.w);
        ((us4*)xb)[i * 2]     = lo;
        ((us4*)xb)[i * 2 + 1] = hi;
    }
}

// ---------------------------------------------------------------------------
// W [k][n] fp32 -> Wt [z][n][k] bf16 (transposed)
// ---------------------------------------------------------------------------
__global__ __launch_bounds__(256) void conv_w(const float* __restrict__ Wq,
                                              const float* __restrict__ Wk,
                                              const float* __restrict__ Wv,
                                              unsigned short* __restrict__ Wt)
{
    const float* W = (blockIdx.z == 0) ? Wq : (blockIdx.z == 1) ? Wk : Wv;
    unsigned short* out = Wt + (size_t)blockIdx.z * F_ * U_;
    __shared__ float tile[32][33];
    const int k0 = blockIdx.x * 32, n0 = blockIdx.y * 32;
    const int r = threadIdx.x >> 5, c = threadIdx.x & 31;
    #pragma unroll
    for (int p = 0; p < 4; ++p)
        tile[p * 8 + r][c] = W[(size_t)(k0 + p * 8 + r) * U_ + n0 + c];
    __syncthreads();
    #pragma unroll
    for (int p = 0; p < 4; ++p)
        out[(size_t)(n0 + p * 8 + r) * F_ + k0 + c] = f2b(tile[c][p * 8 + r]);
}

// ---------------------------------------------------------------------------
// QKV GEMM, bf16 MFMA 16x16x32.  Tile 128x64, 4 waves, BK=32.
// z=0 -> Qb (pre-scaled by 1/sqrt(512)), z=1 -> Kb, z=2 -> Vt [b][u][s].
// ---------------------------------------------------------------------------
__global__ __launch_bounds__(256) void qkv_gemm(
    const unsigned short* __restrict__ xb,
    const unsigned short* __restrict__ Wt,
    unsigned short* __restrict__ Qb,
    unsigned short* __restrict__ Kb,
    unsigned short* __restrict__ Vt)
{
    __shared__ char smem[128 * 65 * 4];                 // 33280 B
    unsigned short* Xs = (unsigned short*)smem;         // [128][32] swizzled
    unsigned short* Ws = Xs + 128 * 32;                 // [64][32]  swizzled
    float* Cs = (float*)smem;                           // [128][65]

    const int z = blockIdx.z;
    const unsigned short* Wz = Wt + (size_t)z * F_ * U_;
    const int bm = blockIdx.x * 128;
    const int bn = blockIdx.y * 64;
    const int t = threadIdx.x;
    const int w = t >> 6, l = t & 63, lr = l & 15, lg = l >> 4;
    const int vxA = (lr >> 1) & 3;       // read-side slot XOR

    f32x4 acc[2][4];
    #pragma unroll
    for (int mt = 0; mt < 2; ++mt)
        #pragma unroll
        for (int nt = 0; nt < 4; ++nt)
            acc[mt][nt] = (f32x4){0.f, 0.f, 0.f, 0.f};

    for (int kc = 0; kc < 16; ++kc) {
        const int k0 = kc * 32;
        __syncthreads();
        #pragma unroll
        for (int p = 0; p < 2; ++p) {
            const int idx = p * 256 + t;
            const int row = idx >> 2, slot = idx & 3;
            const bf16x8 v =
                *(const bf16x8*)&xb[(size_t)(bm + row) * F_ + k0 + slot * 8];
            *(bf16x8*)&Xs[row * 32 + ((slot ^ ((row >> 1) & 3)) * 8)] = v;
        }
        {
            const int row = t >> 2, slot = t & 3;
            const bf16x8 v =
                *(const bf16x8*)&Wz[(size_t)(bn + row) * F_ + k0 + slot * 8];
            *(bf16x8*)&Ws[row * 32 + ((slot ^ ((row >> 1) & 3)) * 8)] = v;
        }
        __syncthreads();
        const bf16x8 a0 = *(const bf16x8*)&Xs[(w * 32 + lr) * 32 + ((lg ^ vxA) * 8)];
        const bf16x8 a1 = *(const bf16x8*)&Xs[(w * 32 + 16 + lr) * 32 + ((lg ^ vxA) * 8)];
        #pragma unroll
        for (int nt = 0; nt < 4; ++nt) {
            const bf16x8 bb = *(const bf16x8*)&Ws[(nt * 16 + lr) * 32 + ((lg ^ vxA) * 8)];
            acc[0][nt] = MFMA(a0, bb, acc[0][nt]);
            acc[1][nt] = MFMA(a1, bb, acc[1][nt]);
        }
    }
    __syncthreads();
    #pragma unroll
    for (int mt = 0; mt < 2; ++mt)
        #pragma unroll
        for (int nt = 0; nt < 4; ++nt)
            #pragma unroll
            for (int j = 0; j < 4; ++j)
                Cs[(w * 32 + mt * 16 + lg * 4 + j) * 65 + nt * 16 + lr] = acc[mt][nt][j];
    __syncthreads();

    if (z < 2) {
        unsigned short* out = (z == 0) ? Qb : Kb;
        const float qs = (z == 0) ? 0.044194173824159216f : 1.0f;  // 1/sqrt(512)
        const int row = t >> 1, half = t & 1;
        unsigned short tmp[32];
        #pragma unroll
        for (int i = 0; i < 32; ++i) tmp[i] = f2b(Cs[row * 65 + half * 32 + i] * qs);
        #pragma unroll
        for (int v = 0; v < 4; ++v)
            *(bf16x8*)&out[(size_t)(bm + row) * U_ + bn + half * 32 + v * 8] =
                *(bf16x8*)&tmp[v * 8];
    } else {
        const int c = t >> 2, s0 = (t & 3) * 32;
        const int b = bm >> 11, sbase = (bm & 2047) + s0;
        unsigned short tmp[32];
        #pragma unroll
        for (int i = 0; i < 32; ++i) tmp[i] = f2b(Cs[(s0 + i) * 65 + c]);
        #pragma unroll
        for (int v = 0; v < 4; ++v)
            *(bf16x8*)&Vt[((size_t)(b * U_ + bn + c)) * S_ + sbase + v * 8] =
                *(bf16x8*)&tmp[v * 8];
    }
}

// ---------------------------------------------------------------------------
// Flash attention v6: split-role waves, 128 q/block, 256 blocks (1/CU).
// QK^T hat:  wave (kh=w&1, g=w>>1) computes 16 keys x 32 q (q-group g).
//            K A-frag read once, feeds 2 MFMAs -> K LDS traffic halved.
// softmax:   per-q max/sum exchanged between the kh-pair via Mp/Lp LDS.
// PV hat:    wave (g=w>>1, uh=w&1) computes 32 q x 256 u via P from LDS
//            -> V LDS traffic halved.  ctx = 32 f32x4.
// XCD-phased batch mapping; reg-prefetch double-staging as R5.
// ---------------------------------------------------------------------------
__global__ __launch_bounds__(512, 2) void attn_mfma(
    const unsigned short* __restrict__ Qb,
    const unsigned short* __restrict__ Kb,
    const unsigned short* __restrict__ Vt,
    float* __restrict__ partial)
{
    __shared__ unsigned short Ks[32 * 516];        // 33.0 KB
    __shared__ unsigned short Vs[512 * 36];        // 36.9 KB
    __shared__ unsigned short Ps[128 * 36];        //  9.2 KB
    __shared__ float Mp[2][128];                   //  1.0 KB
    __shared__ float Lp[2][128];                   //  1.0 KB  -> 81.2 KB

    const int d = blockIdx.x;                      // 0..255
    const int b    = ((d & 7) << 1) | (d >> 7);    // XCD j -> batches 2j,2j+1
    const int qblk = (d >> 3) & 15;                // 0..15
    const int t = threadIdx.x;
    const int w = t >> 6;                          // 0..7
    const int l = t & 63, lr = l & 15, lg = l >> 4;
    const int kh = w & 1, g = w >> 1;              // QK^T role
    const int uh = w & 1;                          // PV role (u-half)

    // ---- hoist Q fragments for 32 queries (pre-scaled by 1/sqrt(512)) ----
    bf16x8 qa[16], qb[16];
    {
        const unsigned short* qg =
            Qb + (size_t)(b * S_ + qblk * 128 + g * 32 + lr) * U_ + lg * 8;
        #pragma unroll
        for (int kc = 0; kc < 16; ++kc) {
            qa[kc] = *(const bf16x8*)(qg + kc * 32);
            qb[kc] = *(const bf16x8*)(qg + 16 * U_ + kc * 32);
        }
    }

    const unsigned short* kgb = Kb + (size_t)b * S_ * U_;
    const unsigned short* vgb = Vt + (size_t)b * U_ * S_;

    bf16x8 kreg[4], vreg[4];
    #pragma unroll
    for (int p = 0; p < 4; ++p) {
        const int id = p * 512 + t;
        kreg[p] = *(const bf16x8*)&kgb[(size_t)(id >> 6) * U_ + (id & 63) * 8];
        vreg[p] = *(const bf16x8*)&vgb[(size_t)(id >> 2) * S_ + (id & 3) * 8];
    }

    f32x4 ctx0[16], ctx1[16];
    #pragma unroll
    for (int nt = 0; nt < 16; ++nt) {
        ctx0[nt] = (f32x4){0.f, 0.f, 0.f, 0.f};
        ctx1[nt] = (f32x4){0.f, 0.f, 0.f, 0.f};
    }
    float m_a = -1e30f, m_b = -1e30f, l_a = 0.f, l_b = 0.f;

    for (int kb = 0; kb < S_ / 32; ++kb) {
        __syncthreads();                 // (1) prev readers done
        #pragma unroll
        for (int p = 0; p < 4; ++p) {
            const int id = p * 512 + t;
            *(bf16x8*)&Ks[(id >> 6) * 516 + (id & 63) * 8] = kreg[p];
            *(bf16x8*)&Vs[(id >> 2) * 36 + (id & 3) * 8]   = vreg[p];
        }
        __syncthreads();                 // (2) tiles visible

        const int nkb = (kb < S_ / 32 - 1) ? kb + 1 : kb;
        #pragma unroll
        for (int p = 0; p < 4; ++p) {
            const int id = p * 512 + t;
            kreg[p] = *(const bf16x8*)&kgb[(size_t)(nkb * 32 + (id >> 6)) * U_ + (id & 63) * 8];
            vreg[p] = *(const bf16x8*)&vgb[(size_t)(id >> 2) * S_ + nkb * 32 + (id & 3) * 8];
        }

        // ---- QK^T: S^T[16 keys (kh), 32 q (group g)] ----
        f32x4 sa = (f32x4){0.f, 0.f, 0.f, 0.f};
        f32x4 sb = (f32x4){0.f, 0.f, 0.f, 0.f};
        #pragma unroll
        for (int kc = 0; kc < 16; ++kc) {
            const bf16x8 kf = *(const bf16x8*)&Ks[(kh * 16 + lr) * 516 + kc * 32 + lg * 8];
            sa = MFMA(kf, qa[kc], sa);
            sb = MFMA(kf, qb[kc], sb);
        }

        // ---- per-q partial max over the wave's 16 keys ----
        float mba = fmaxf(fmaxf(sa[0], sa[1]), fmaxf(sa[2], sa[3]));
        float mbb = fmaxf(fmaxf(sb[0], sb[1]), fmaxf(sb[2], sb[3]));
        mba = fmaxf(mba, __shfl_xor(mba, 16)); mba = fmaxf(mba, __shfl_xor(mba, 32));
        mbb = fmaxf(mbb, __shfl_xor(mbb, 16)); mbb = fmaxf(mbb, __shfl_xor(mbb, 32));
        if (lg == 0) {
            Mp[kh][g * 32 + lr]      = mba;
            Mp[kh][g * 32 + 16 + lr] = mbb;
        }
        __syncthreads();                 // (3) partial maxima visible
        const float mca = fmaxf(mba, Mp[kh ^ 1][g * 32 + lr]);
        const float mcb = fmaxf(mbb, Mp[kh ^ 1][g * 32 + 16 + lr]);

        // ---- deferred rescale (THR=8); pair waves decide identically ----
        const bool ok = (mca <= m_a + 8.f) && (mcb <= m_b + 8.f);
        if (!__all(ok)) {
            const float mna = fmaxf(m_a, mca), mnb = fmaxf(m_b, mcb);
            const float aa = __expf(m_a - mna), ab = __expf(m_b - mnb);
            float ra[4], rb[4];
            #pragma unroll
            for (int j = 0; j < 4; ++j) {
                ra[j] = __shfl(aa, (l & 48) | (lg * 4 + j));
                rb[j] = __shfl(ab, (l & 48) | (lg * 4 + j));
            }
            #pragma unroll
            for (int nt = 0; nt < 16; ++nt)
                #pragma unroll
                for (int j = 0; j < 4; ++j) {
                    ctx0[nt][j] *= ra[j];
                    ctx1[nt][j] *= rb[j];
                }
            l_a *= aa; l_b *= ab; m_a = mna; m_b = mnb;
        }

        // ---- exp + per-q partial sums ----
        float pa[4], pb[4];
        float la = 0.f, lb = 0.f;
        #pragma unroll
        for (int j = 0; j < 4; ++j) {
            pa[j] = __expf(sa[j] - m_a); la += pa[j];
            pb[j] = __expf(sb[j] - m_b); lb += pb[j];
        }
        la += __shfl_xor(la, 16); la += __shfl_xor(la, 32);
        lb += __shfl_xor(lb, 16); lb += __shfl_xor(lb, 32);
        if (lg == 0) {
            Lp[kh][g * 32 + lr]      = la;
            Lp[kh][g * 32 + 16 + lr] = lb;
        }

        // ---- write P quarter-tiles: Ps[q][key] ----
        us4 wa, wb;
        wa.x = f2b(pa[0]); wa.y = f2b(pa[1]); wa.z = f2b(pa[2]); wa.w = f2b(pa[3]);
        wb.x = f2b(pb[0]); wb.y = f2b(pb[1]); wb.z = f2b(pb[2]); wb.w = f2b(pb[3]);
        *(us4*)&Ps[(g * 32 + lr) * 36 + kh * 16 + lg * 4]      = wa;
        *(us4*)&Ps[(g * 32 + 16 + lr) * 36 + kh * 16 + lg * 4] = wb;
        __syncthreads();                 // (4) P, Lp visible

        l_a += la + Lp[kh ^ 1][g * 32 + lr];
        l_b += lb + Lp[kh ^ 1][g * 32 + 16 + lr];

        // ---- PV: ctx[32q x 256u], u-half uh ----
        const bf16x8 pf0 = *(const bf16x8*)&Ps[(g * 32 + lr) * 36 + lg * 8];
        const bf16x8 pf1 = *(const bf16x8*)&Ps[(g * 32 + 16 + lr) * 36 + lg * 8];
        #pragma unroll
        for (int nt = 0; nt < 16; ++nt) {
            const bf16x8 vf =
                *(const bf16x8*)&Vs[(uh * 256 + nt * 16 + lr) * 36 + lg * 8];
            ctx0[nt] = MFMA(pf0, vf, ctx0[nt]);
            ctx1[nt] = MFMA(pf1, vf, ctx1[nt]);
        }
    }

    // ---- epilogue: normalize, sum the 32 q, combine 4 q-groups ----
    const float inva = 1.f / l_a, invb = 1.f / l_b;
    float invra[4], invrb[4];
    #pragma unroll
    for (int j = 0; j < 4; ++j) {
        invra[j] = __shfl(inva, (l & 48) | (lg * 4 + j));
        invrb[j] = __shfl(invb, (l & 48) | (lg * 4 + j));
    }

    float* SumBuf = (float*)Ks;           // overlay: [4 g][512 u]
    #pragma unroll
    for (int nt = 0; nt < 16; ++nt) {
        float s = ctx0[nt][0] * invra[0] + ctx0[nt][1] * invra[1]
                + ctx0[nt][2] * invra[2] + ctx0[nt][3] * invra[3]
                + ctx1[nt][0] * invrb[0] + ctx1[nt][1] * invrb[1]
                + ctx1[nt][2] * invrb[2] + ctx1[nt][3] * invrb[3];
        s += __shfl_xor(s, 16);
        s += __shfl_xor(s, 32);
        if (lg == 0) SumBuf[g * 512 + uh * 256 + nt * 16 + lr] = s;
    }
    __syncthreads();
    {
        const int u = t;                  // 512 threads cover 512 u
        const float s = SumBuf[u] + SumBuf[512 + u]
                      + SumBuf[1024 + u] + SumBuf[1536 + u];
        partial[(size_t)(b * 16 + qblk) * U_ + u] = s;
    }
}

// ---------------------------------------------------------------------------
// partial [16][16][512] -> out [16][512], mean over S
// ---------------------------------------------------------------------------
__global__ __launch_bounds__(256) void reduce_mean(
    const float* __restrict__ partial, float* __restrict__ out)
{
    const int b = blockIdx.x;
    for (int u = threadIdx.x; u < U_; u += 256) {
        float s = 0.f;
        #pragma unroll
        for (int p = 0; p < 16; ++p)
            s += partial[(size_t)(b * 16 + p) * U_ + u];
        out[b * U_ + u] = s * (1.0f / (float)S_);
    }
}

extern "C" void kernel_launch(void* const* d_in, const int* in_sizes, int n_in,
                              void* d_out, int out_size, void* d_ws, size_t ws_size,
                              hipStream_t stream)
{
    const float* x  = (const float*)d_in[0];
    const float* Wq = (const float*)d_in[1];
    const float* Wk = (const float*)d_in[2];
    const float* Wv = (const float*)d_in[3];
    float* out = (float*)d_out;

    unsigned short* ws = (unsigned short*)d_ws;
    const size_t XB_OFF = 0;                               // [32768][512] bf16
    const size_t WT_OFF = XB_OFF + (size_t)NROWS * F_;     // 3x[512][512] bf16
    const size_t QB_OFF = WT_OFF + 3ull * F_ * U_;
    const size_t KB_OFF = QB_OFF + (size_t)NROWS * U_;
    const size_t VT_OFF = KB_OFF + (size_t)NROWS * U_;
    const size_t END_USH = VT_OFF + (size_t)NROWS * U_;
    float* partial = (float*)(ws + END_USH);               // [16][16][512] fp32
    const size_t need = END_USH * 2 + (size_t)B_ * 16 * U_ * 4;
    if (ws_size < need) return;

    unsigned short* xb = ws + XB_OFF;
    unsigned short* Wt = ws + WT_OFF;
    unsigned short* Qb = ws + QB_OFF;
    unsigned short* Kb = ws + KB_OFF;
    unsigned short* Vt = ws + VT_OFF;

    conv_x<<<2048, 256, 0, stream>>>(x, xb);
    conv_w<<<dim3(16, 16, 3), 256, 0, stream>>>(Wq, Wk, Wv, Wt);
    qkv_gemm<<<dim3(NROWS / 128, U_ / 64, 3), 256, 0, stream>>>(xb, Wt, Qb, Kb, Vt);
    attn_mfma<<<256, 512, 0, stream>>>(Qb, Kb, Vt, partial);
    reduce_mean<<<B_, 256, 0, stream>>>(partial, out);
}